// Round 1
// 1006.226 us; speedup vs baseline: 1.1073x; 1.1073x over previous
//
#include <hip/hip_runtime.h>
#include <cstdint>

#define S_   2048
#define H_   4096
#define NH_  32
#define NKV_ 8
#define HD_  128

typedef short  short8  __attribute__((ext_vector_type(8)));
typedef float  floatx4 __attribute__((ext_vector_type(4)));
typedef unsigned int uintx2 __attribute__((ext_vector_type(2)));
typedef unsigned int uint32;
typedef unsigned short ushort16;

__device__ inline unsigned int pk_bf16(float a, float b) {
  unsigned int ua = __builtin_bit_cast(unsigned int, a) + 0x8000u;
  unsigned int ub = __builtin_bit_cast(unsigned int, b) + 0x8000u;
  return __builtin_amdgcn_perm(ub, ua, 0x07060302u);
}
__device__ inline unsigned short f32_bf16(float a) {
  return (unsigned short)((__builtin_bit_cast(unsigned int, a) + 0x8000u) >> 16);
}

__device__ inline void gld16(const ushort16* g, ushort16* l) {
  __builtin_amdgcn_global_load_lds((const __attribute__((address_space(1))) void*)g,
                                   (__attribute__((address_space(3))) void*)l, 16, 0, 0);
}

// fp32 -> bf16 elementwise, 4 elems/thread. grid = n/1024.
__global__ __launch_bounds__(256)
void cvt_bf16(const float* __restrict__ in, uint32* __restrict__ out) {
  const int idx = blockIdx.x * 256 + threadIdx.x;
  floatx4 v = ((const floatx4*)in)[idx];
  uintx2 o;
  o[0] = pk_bf16(v[0], v[1]);
  o[1] = pk_bf16(v[2], v[3]);
  ((uintx2*)out)[idx] = o;
}

// bf16 transpose: in [4096 x 1024] -> out [1024 x 4096]. grid (16, 64), 256 thr.
__global__ __launch_bounds__(256)
void transp(const ushort16* __restrict__ in, ushort16* __restrict__ out) {
  __shared__ __align__(16) ushort16 T[64 * 66];
  const int tid = threadIdx.x, wave = tid >> 6, j = tid & 63;
  const int c0 = blockIdx.x * 64, r0 = blockIdx.y * 64;
#pragma unroll
  for (int it = 0; it < 16; it++) {
    const int i = it * 4 + wave;
    T[i * 66 + j] = in[(size_t)(r0 + i) * 1024 + c0 + j];
  }
  __syncthreads();
#pragma unroll
  for (int it = 0; it < 16; it++) {
    const int i = it * 4 + wave;
    out[(size_t)(c0 + i) * 4096 + r0 + j] = T[j * 66 + i];
  }
}

// Y(M x N) = A(M x 4096) @ B(N x 4096)^T, all bf16 in, m97-style 128x128 tile.
template<bool ROPE, bool SCALE, bool OUTF32>
__global__ __launch_bounds__(256)
void gemm128(const ushort16* __restrict__ A, const ushort16* __restrict__ B,
             void* __restrict__ Y, int N,
             const float* __restrict__ cosT, const float* __restrict__ sinT)
{
  constexpr int K = H_;
  __shared__ __align__(16) ushort16 As[128 * 32];
  __shared__ __align__(16) ushort16 Bs[128 * 32];
  const int bn = blockIdx.x * 128, bm = blockIdx.y * 128;
  const int tid = threadIdx.x, wave = tid >> 6, lane = tid & 63;
  const int l15 = lane & 15, quad = lane >> 4;
  const int wr = (wave & 1) * 64, wc = (wave >> 1) * 64;

  const int crow = lane >> 2;
  const int ckb  = (lane & 3) ^ ((lane >> 3) & 3);
  const int q0 = wave * 2, q1 = q0 + 1;
  const ushort16* gA0 = A + (size_t)(bm + q0 * 16 + crow) * K + ckb * 8;
  const ushort16* gA1 = A + (size_t)(bm + q1 * 16 + crow) * K + ckb * 8;
  const ushort16* gB0 = B + (size_t)(bn + q0 * 16 + crow) * K + ckb * 8;
  const ushort16* gB1 = B + (size_t)(bn + q1 * 16 + crow) * K + ckb * 8;
  ushort16* lA0 = As + q0 * 512;
  ushort16* lA1 = As + q1 * 512;
  ushort16* lB0 = Bs + q0 * 512;
  ushort16* lB1 = Bs + q1 * 512;

  const int slot = quad ^ ((l15 >> 1) & 3);
  int aoff[4], boff[4];
#pragma unroll
  for (int t = 0; t < 4; t++) {
    aoff[t] = (wr + t * 16 + l15) * 32 + slot * 8;
    boff[t] = (wc + t * 16 + l15) * 32 + slot * 8;
  }

  floatx4 acc[4][4] = {};

  for (int k0 = 0; k0 < K; k0 += 32) {
    __syncthreads();
    gld16(gA0 + k0, lA0);
    gld16(gA1 + k0, lA1);
    gld16(gB0 + k0, lB0);
    gld16(gB1 + k0, lB1);
    __syncthreads();

    short8 af[4], bf[4];
#pragma unroll
    for (int t = 0; t < 4; t++) af[t] = *(const short8*)(As + aoff[t]);
#pragma unroll
    for (int t = 0; t < 4; t++) bf[t] = *(const short8*)(Bs + boff[t]);
#pragma unroll
    for (int mt = 0; mt < 4; mt++)
#pragma unroll
      for (int nt = 0; nt < 4; nt++)
        acc[mt][nt] = __builtin_amdgcn_mfma_f32_16x16x32_bf16(af[mt], bf[nt], acc[mt][nt], 0, 0, 0);
  }

#pragma unroll
  for (int mt = 0; mt < 4; mt++) {
#pragma unroll
    for (int nt = 0; nt < 4; nt++) {
      const int col = bn + wc + nt * 16 + l15;
#pragma unroll
      for (int r = 0; r < 4; r++) {
        const int row = bm + wr + mt * 16 + quad * 4 + r;
        float v = acc[mt][nt][r];
        if (ROPE) {
          float other = __shfl_xor(v, 1, 64);
          const int pos = row & (S_ - 1);
          const int i   = (col & (HD_ - 1)) >> 1;
          const float c  = cosT[pos * (HD_ / 2) + i];
          const float sn = sinT[pos * (HD_ / 2) + i];
          v = (lane & 1) ? (other * sn + v * c) : (v * c - other * sn);
        }
        if (SCALE) v *= 0.08838834764831845f;
        if (OUTF32) ((float*)Y)[(size_t)row * N + col] = v;
        else        ((ushort16*)Y)[(size_t)row * N + col] = f32_bf16(v);
      }
    }
  }
}

// MFMA flash attention v2.
// grid (S/128, B*NH), 256 thr = 4 waves, 32 q-rows/wave (2 m-tiles of 16).
// Double-buffered K / V^T tiles staged via global_load_lds width=16 with
// 16B-chunk XOR swizzle (pre-swizzled global source, linear LDS dest);
// all ds_read_b128 fragment reads are bank-conflict-free (minimal 8 cyc).
// One barrier per KV tile; next tile issued before compute (T3-minimum).
__global__ __launch_bounds__(256, 2)
void flash_mfma(const ushort16* __restrict__ Qg, const ushort16* __restrict__ Kg,
                const ushort16* __restrict__ Vtg, ushort16* __restrict__ Cg)
{
  __shared__ __align__(16) ushort16 Ks[2][64 * 128];   // [key][dim], chunk-swizzled, 16 KB each
  __shared__ __align__(16) ushort16 VT[2][128 * 64];   // [dim][key], chunk-swizzled, 16 KB each
  __shared__ __align__(16) ushort16 Ps[4][32 * 64];    // per-wave P [qrow][key], chunk-swizzled

  const int tid = threadIdx.x, wave = tid >> 6, lane = tid & 63;
  const int l15 = lane & 15, quad = lane >> 4;
  const int qb = (S_ / 128 - 1) - blockIdx.x;          // long columns first (tail fill)
  const int by = blockIdx.y;
  const int b = by >> 5, h = by & 31, kh = h >> 2;
  const int qrow0 = qb * 128 + wave * 32;

  // Q A-frags direct from global (scale pre-folded): A[m=l15][k=quad*8+j]
  short8 aq[2][4];
  const ushort16* qbase = Qg + (size_t)(b * S_ + qrow0 + l15) * 4096 + h * 128 + quad * 8;
#pragma unroll
  for (int mt = 0; mt < 2; mt++)
#pragma unroll
    for (int ks = 0; ks < 4; ks++)
      aq[mt][ks] = *(const short8*)(qbase + mt * 16 * 4096 + ks * 32);

  // staging source offsets (16B chunks, XOR pre-swizzle so linear LDS = swizzled layout)
  int kOff[4], vOff[4];
#pragma unroll
  for (int it = 0; it < 4; it++) {
    const int s = (wave * 4 + it) * 64 + lane;
    const int rK = s >> 4, cK = (s & 15) ^ (rK & 15);   // K tile: 64 rows x 16 chunks
    kOff[it] = rK * 1024 + cK * 8;
    const int dV = s >> 3, cV = (s & 7) ^ (dV & 7);     // VT tile: 128 rows x 8 chunks
    vOff[it] = dV * 4096 + cV * 8;
  }
  const ushort16* Kbase = Kg + (size_t)(b * S_) * 1024 + kh * 128;
  const ushort16* Vbase = Vtg + (size_t)(kh * 128) * 4096 + (size_t)b * S_;

  const int ktmax = 2 * qb + 1;

  // prologue: stage kt=0 into buf 0
#pragma unroll
  for (int it = 0; it < 4; it++) {
    gld16(Kbase + kOff[it], &Ks[0][0] + (wave * 4 + it) * 512);
    gld16(Vbase + vOff[it], &VT[0][0] + (wave * 4 + it) * 512);
  }
  __syncthreads();   // drains vmcnt(0): buf0 ready

  floatx4 o_acc[2][8] = {};
  float m_i[2][4], l_i[2][4];
#pragma unroll
  for (int mt = 0; mt < 2; mt++)
#pragma unroll
    for (int r = 0; r < 4; r++) { m_i[mt][r] = -1e30f; l_i[mt][r] = 0.f; }
  ushort16* Pw = Ps[wave];

  for (int kt = 0; kt <= ktmax; ++kt) {
    const int cur = kt & 1;
    const ushort16* KsC = &Ks[cur][0];
    const ushort16* VTC = &VT[cur][0];

    // issue next tile's staging before compute (latency hidden under MFMA/softmax)
    if (kt < ktmax) {
      ushort16* KsN = &Ks[cur ^ 1][0];
      ushort16* VTN = &VT[cur ^ 1][0];
      const ushort16* ktb = Kbase + (size_t)(kt + 1) * 65536;
      const ushort16* vtb = Vbase + (kt + 1) * 64;
#pragma unroll
      for (int it = 0; it < 4; it++) {
        gld16(ktb + kOff[it], KsN + (wave * 4 + it) * 512);
        gld16(vtb + vOff[it], VTN + (wave * 4 + it) * 512);
      }
    }

    const bool active = (kt * 64 <= qrow0 + 31);
    if (active) {
      // S = Q K^T : K-frags reused across both m-tiles
      floatx4 sc[2][4] = {};
      __builtin_amdgcn_s_setprio(1);
#pragma unroll
      for (int nt = 0; nt < 4; nt++)
#pragma unroll
        for (int ks = 0; ks < 4; ks++) {
          short8 bk = *(const short8*)(KsC + (nt * 16 + l15) * 128 + (((ks * 4 + quad) ^ l15) * 8));
          sc[0][nt] = __builtin_amdgcn_mfma_f32_16x16x32_bf16(aq[0][ks], bk, sc[0][nt], 0, 0, 0);
          sc[1][nt] = __builtin_amdgcn_mfma_f32_16x16x32_bf16(aq[1][ks], bk, sc[1][nt], 0, 0, 0);
        }
      __builtin_amdgcn_s_setprio(0);

      // causal mask (only near the diagonal)
      if (kt * 64 + 63 > qrow0) {
#pragma unroll
        for (int mt = 0; mt < 2; mt++)
#pragma unroll
          for (int nt = 0; nt < 4; nt++)
#pragma unroll
            for (int r = 0; r < 4; r++)
              if (kt * 64 + nt * 16 + l15 > qrow0 + mt * 16 + quad * 4 + r) sc[mt][nt][r] = -1e30f;
      }

      // online softmax; rows quad*4+r shared across the 16 lanes of a quad
#pragma unroll
      for (int mt = 0; mt < 2; mt++) {
#pragma unroll
        for (int r = 0; r < 4; r++) {
          float mx = fmaxf(fmaxf(sc[mt][0][r], sc[mt][1][r]), fmaxf(sc[mt][2][r], sc[mt][3][r]));
#pragma unroll
          for (int off = 1; off < 16; off <<= 1) mx = fmaxf(mx, __shfl_xor(mx, off, 64));
          const float mn = fmaxf(m_i[mt][r], mx);
          const float alpha = __expf(m_i[mt][r] - mn);
          m_i[mt][r] = mn;
          const int prow = mt * 16 + quad * 4 + r;
          float rs = 0.f;
#pragma unroll
          for (int nt = 0; nt < 4; nt++) {
            const float p = __expf(sc[mt][nt][r] - mn);
            rs += p;
            const int key = nt * 16 + l15;
            Pw[prow * 64 + ((((key >> 3) ^ (prow & 7)) * 8) + (key & 7))] = f32_bf16(p);
          }
#pragma unroll
          for (int off = 1; off < 16; off <<= 1) rs += __shfl_xor(rs, off, 64);
          l_i[mt][r] = l_i[mt][r] * alpha + rs;
#pragma unroll
          for (int dt = 0; dt < 8; dt++) o_acc[mt][dt][r] *= alpha;
        }
      }

      // O += P V : V^T-frags reused across both m-tiles (same-wave LDS W->R, DS in-order)
      __builtin_amdgcn_s_setprio(1);
#pragma unroll
      for (int ks2 = 0; ks2 < 2; ks2++) {
        short8 ap0 = *(const short8*)(Pw + l15 * 64 + (((ks2 * 4 + quad) ^ (l15 & 7)) * 8));
        short8 ap1 = *(const short8*)(Pw + (16 + l15) * 64 + (((ks2 * 4 + quad) ^ (l15 & 7)) * 8));
#pragma unroll
        for (int dt = 0; dt < 8; dt++) {
          const int d = dt * 16 + l15;
          short8 bv = *(const short8*)(VTC + d * 64 + (((ks2 * 4 + quad) ^ (d & 7)) * 8));
          o_acc[0][dt] = __builtin_amdgcn_mfma_f32_16x16x32_bf16(ap0, bv, o_acc[0][dt], 0, 0, 0);
          o_acc[1][dt] = __builtin_amdgcn_mfma_f32_16x16x32_bf16(ap1, bv, o_acc[1][dt], 0, 0, 0);
        }
      }
      __builtin_amdgcn_s_setprio(0);
    }
    __syncthreads();   // drains vmcnt(0): next buf staged; cur buf free to overwrite
  }

  float vinv[2][4];
#pragma unroll
  for (int mt = 0; mt < 2; mt++)
#pragma unroll
    for (int r = 0; r < 4; r++) vinv[mt][r] = 1.f / l_i[mt][r];
#pragma unroll
  for (int mt = 0; mt < 2; mt++)
#pragma unroll
    for (int dt = 0; dt < 8; dt++)
#pragma unroll
      for (int r = 0; r < 4; r++)
        Cg[(size_t)(b * S_ + qrow0 + mt * 16 + quad * 4 + r) * 4096 + h * 128 + dt * 16 + l15] =
            f32_bf16(o_acc[mt][dt][r] * vinv[mt][r]);
}

extern "C" void kernel_launch(void* const* d_in, const int* in_sizes, int n_in,
                              void* d_out, int out_size, void* d_ws, size_t ws_size,
                              hipStream_t stream) {
  const float* hs   = (const float*)d_in[0];
  const float* cosT = (const float*)d_in[1];
  const float* sinT = (const float*)d_in[2];
  const float* Wq = (const float*)d_in[5];
  const float* Wk = (const float*)d_in[6];
  const float* Wv = (const float*)d_in[7];
  const float* Wo = (const float*)d_in[8];
  float* out = (float*)d_out;

  char* ws = (char*)d_ws;
  ushort16* hsB = (ushort16*)(ws);                      // 33.5 MB  (also reused as CB)
  ushort16* QB  = (ushort16*)(ws + 33554432);           // 33.5 MB
  ushort16* KB  = (ushort16*)(ws + 67108864);           // 8.4 MB
  ushort16* VB  = (ushort16*)(ws + 75497472);           // 8.4 MB
  ushort16* VTg = (ushort16*)(ws + 83886080);           // 8.4 MB
  ushort16* WB  = (ushort16*)(ws + 92274688);           // 33.5 MB (per-GEMM weight buf)
  ushort16* CB  = hsB;                                  // reuse hs region after V GEMM

  dim3 blk(256);
  cvt_bf16<<<dim3(16384), blk, 0, stream>>>(hs, (uint32*)hsB);
  cvt_bf16<<<dim3(16384), blk, 0, stream>>>(Wq, (uint32*)WB);
  gemm128<true,  true,  false><<<dim3(32, 32), blk, 0, stream>>>(hsB, WB, QB, 4096, cosT, sinT);
  cvt_bf16<<<dim3(4096),  blk, 0, stream>>>(Wk, (uint32*)WB);
  gemm128<true,  false, false><<<dim3(8, 32),  blk, 0, stream>>>(hsB, WB, KB, 1024, cosT, sinT);
  cvt_bf16<<<dim3(4096),  blk, 0, stream>>>(Wv, (uint32*)WB);
  gemm128<false, false, false><<<dim3(8, 32),  blk, 0, stream>>>(hsB, WB, VB, 1024, cosT, sinT);
  transp<<<dim3(16, 64), blk, 0, stream>>>(VB, VTg);
  flash_mfma<<<dim3(S_ / 128, 2 * NH_), blk, 0, stream>>>(QB, KB, VTg, CB);
  cvt_bf16<<<dim3(16384), blk, 0, stream>>>(Wo, (uint32*)WB);
  gemm128<false, false, true><<<dim3(32, 32), blk, 0, stream>>>(CB, WB, out, 4096, cosT, sinT);
}

// Round 2
// 999.964 us; speedup vs baseline: 1.1143x; 1.0063x over previous
//
#include <hip/hip_runtime.h>
#include <cstdint>

#define S_   2048
#define H_   4096
#define NH_  32
#define NKV_ 8
#define HD_  128

typedef short  short8  __attribute__((ext_vector_type(8)));
typedef float  floatx4 __attribute__((ext_vector_type(4)));
typedef unsigned int uintx2 __attribute__((ext_vector_type(2)));
typedef unsigned int uint32;
typedef unsigned short ushort16;

__device__ inline unsigned int pk_bf16(float a, float b) {
  unsigned int ua = __builtin_bit_cast(unsigned int, a) + 0x8000u;
  unsigned int ub = __builtin_bit_cast(unsigned int, b) + 0x8000u;
  return __builtin_amdgcn_perm(ub, ua, 0x07060302u);
}
__device__ inline unsigned short f32_bf16(float a) {
  return (unsigned short)((__builtin_bit_cast(unsigned int, a) + 0x8000u) >> 16);
}

__device__ inline void gld16(const ushort16* g, ushort16* l) {
  __builtin_amdgcn_global_load_lds((const __attribute__((address_space(1))) void*)g,
                                   (__attribute__((address_space(3))) void*)l, 16, 0, 0);
}

// fp32 -> bf16 elementwise, 4 elems/thread. grid = n/1024.
__global__ __launch_bounds__(256)
void cvt_bf16(const float* __restrict__ in, uint32* __restrict__ out) {
  const int idx = blockIdx.x * 256 + threadIdx.x;
  floatx4 v = ((const floatx4*)in)[idx];
  uintx2 o;
  o[0] = pk_bf16(v[0], v[1]);
  o[1] = pk_bf16(v[2], v[3]);
  ((uintx2*)out)[idx] = o;
}

// bf16 transpose: in [4096 x 1024] -> out [1024 x 4096]. grid (16, 64), 256 thr.
__global__ __launch_bounds__(256)
void transp(const ushort16* __restrict__ in, ushort16* __restrict__ out) {
  __shared__ __align__(16) ushort16 T[64 * 66];
  const int tid = threadIdx.x, wave = tid >> 6, j = tid & 63;
  const int c0 = blockIdx.x * 64, r0 = blockIdx.y * 64;
#pragma unroll
  for (int it = 0; it < 16; it++) {
    const int i = it * 4 + wave;
    T[i * 66 + j] = in[(size_t)(r0 + i) * 1024 + c0 + j];
  }
  __syncthreads();
#pragma unroll
  for (int it = 0; it < 16; it++) {
    const int i = it * 4 + wave;
    out[(size_t)(c0 + i) * 4096 + r0 + j] = T[j * 66 + i];
  }
}

// Y(M x N) = A(M x 4096) @ B(N x 4096)^T, all bf16 in, m97-style 128x128 tile.
template<bool ROPE, bool SCALE, bool OUTF32>
__global__ __launch_bounds__(256)
void gemm128(const ushort16* __restrict__ A, const ushort16* __restrict__ B,
             void* __restrict__ Y, int N,
             const float* __restrict__ cosT, const float* __restrict__ sinT)
{
  constexpr int K = H_;
  __shared__ __align__(16) ushort16 As[128 * 32];
  __shared__ __align__(16) ushort16 Bs[128 * 32];
  const int bn = blockIdx.x * 128, bm = blockIdx.y * 128;
  const int tid = threadIdx.x, wave = tid >> 6, lane = tid & 63;
  const int l15 = lane & 15, quad = lane >> 4;
  const int wr = (wave & 1) * 64, wc = (wave >> 1) * 64;

  const int crow = lane >> 2;
  const int ckb  = (lane & 3) ^ ((lane >> 3) & 3);
  const int q0 = wave * 2, q1 = q0 + 1;
  const ushort16* gA0 = A + (size_t)(bm + q0 * 16 + crow) * K + ckb * 8;
  const ushort16* gA1 = A + (size_t)(bm + q1 * 16 + crow) * K + ckb * 8;
  const ushort16* gB0 = B + (size_t)(bn + q0 * 16 + crow) * K + ckb * 8;
  const ushort16* gB1 = B + (size_t)(bn + q1 * 16 + crow) * K + ckb * 8;
  ushort16* lA0 = As + q0 * 512;
  ushort16* lA1 = As + q1 * 512;
  ushort16* lB0 = Bs + q0 * 512;
  ushort16* lB1 = Bs + q1 * 512;

  const int slot = quad ^ ((l15 >> 1) & 3);
  int aoff[4], boff[4];
#pragma unroll
  for (int t = 0; t < 4; t++) {
    aoff[t] = (wr + t * 16 + l15) * 32 + slot * 8;
    boff[t] = (wc + t * 16 + l15) * 32 + slot * 8;
  }

  floatx4 acc[4][4] = {};

  for (int k0 = 0; k0 < K; k0 += 32) {
    __syncthreads();
    gld16(gA0 + k0, lA0);
    gld16(gA1 + k0, lA1);
    gld16(gB0 + k0, lB0);
    gld16(gB1 + k0, lB1);
    __syncthreads();

    short8 af[4], bf[4];
#pragma unroll
    for (int t = 0; t < 4; t++) af[t] = *(const short8*)(As + aoff[t]);
#pragma unroll
    for (int t = 0; t < 4; t++) bf[t] = *(const short8*)(Bs + boff[t]);
#pragma unroll
    for (int mt = 0; mt < 4; mt++)
#pragma unroll
      for (int nt = 0; nt < 4; nt++)
        acc[mt][nt] = __builtin_amdgcn_mfma_f32_16x16x32_bf16(af[mt], bf[nt], acc[mt][nt], 0, 0, 0);
  }

#pragma unroll
  for (int mt = 0; mt < 4; mt++) {
#pragma unroll
    for (int nt = 0; nt < 4; nt++) {
      const int col = bn + wc + nt * 16 + l15;
#pragma unroll
      for (int r = 0; r < 4; r++) {
        const int row = bm + wr + mt * 16 + quad * 4 + r;
        float v = acc[mt][nt][r];
        if (ROPE) {
          float other = __shfl_xor(v, 1, 64);
          const int pos = row & (S_ - 1);
          const int i   = (col & (HD_ - 1)) >> 1;
          const float c  = cosT[pos * (HD_ / 2) + i];
          const float sn = sinT[pos * (HD_ / 2) + i];
          v = (lane & 1) ? (other * sn + v * c) : (v * c - other * sn);
        }
        if (SCALE) v *= 0.08838834764831845f;
        if (OUTF32) ((float*)Y)[(size_t)row * N + col] = v;
        else        ((ushort16*)Y)[(size_t)row * N + col] = f32_bf16(v);
      }
    }
  }
}

// MFMA flash attention v3.
// grid (S/256, B*NH), 512 thr = 8 waves, 32 q-rows/wave (2 m-tiles of 16).
// Triple-buffered K / V^T tiles (depth-2 prefetch pipeline) staged via
// global_load_lds width=16, 16B-chunk XOR swizzle (pre-swizzled global source).
// Raw s_barrier + counted s_waitcnt vmcnt(4): per-tile load latency fully hidden
// (loads complete two tiles after issue, never drained to 0 in steady state).
// T13 defer-max (THR=8) skips o_acc rescale on most tiles.
__global__ __launch_bounds__(512, 2)
void flash_mfma(const ushort16* __restrict__ Qg, const ushort16* __restrict__ Kg,
                const ushort16* __restrict__ Vtg, ushort16* __restrict__ Cg)
{
  __shared__ __align__(16) ushort16 Ks[3][64 * 128];   // [key][dim], chunk-swizzled, 16 KB each
  __shared__ __align__(16) ushort16 VT[3][128 * 64];   // [dim][key], chunk-swizzled, 16 KB each
  __shared__ __align__(16) ushort16 Ps[8][32 * 64];    // per-wave P [qrow][key], chunk-swizzled

  const int tid = threadIdx.x, wave = tid >> 6, lane = tid & 63;
  const int l15 = lane & 15, quad = lane >> 4;
  const int qb = (S_ / 256 - 1) - blockIdx.x;          // longest blocks dispatch first (LPT)
  const int by = blockIdx.y;
  const int b = by >> 5, h = by & 31, kh = h >> 2;
  const int qrow0 = qb * 256 + wave * 32;

  // Q A-frags direct from global (scale pre-folded): A[m=l15][k=quad*8+j]
  short8 aq[2][4];
  const ushort16* qbase = Qg + (size_t)(b * S_ + qrow0 + l15) * 4096 + h * 128 + quad * 8;
#pragma unroll
  for (int mt = 0; mt < 2; mt++)
#pragma unroll
    for (int ks = 0; ks < 4; ks++)
      aq[mt][ks] = *(const short8*)(qbase + mt * 16 * 4096 + ks * 32);

  // staging source offsets: 1024 16B-chunks per tile, 2 batches x 512 threads.
  // XOR pre-swizzle on the global source; LDS dest stays linear (rule #21).
  int kOff[2], vOff[2];
#pragma unroll
  for (int it = 0; it < 2; it++) {
    const int s = it * 512 + tid;
    const int rK = s >> 4, cK = (s & 15) ^ (rK & 15);   // K tile: 64 rows x 16 chunks
    kOff[it] = rK * 1024 + cK * 8;
    const int dV = s >> 3, cV = (s & 7) ^ (dV & 7);     // VT tile: 128 rows x 8 chunks
    vOff[it] = dV * 4096 + cV * 8;
  }
  const ushort16* Kbase = Kg + (size_t)(b * S_) * 1024 + kh * 128;
  const ushort16* Vbase = Vtg + (size_t)(kh * 128) * 4096 + (size_t)b * S_;
  const int ktmax = 4 * qb + 3;

  auto STAGE = [&](int kt, int buf) {
    const ushort16* kg = Kbase + (size_t)kt * 65536;
    const ushort16* vg = Vbase + kt * 64;
    ushort16* kd = &Ks[buf][0];
    ushort16* vd = &VT[buf][0];
#pragma unroll
    for (int it = 0; it < 2; it++) {
      gld16(kg + kOff[it], kd + it * 4096 + wave * 512);
      gld16(vg + vOff[it], vd + it * 4096 + wave * 512);
    }
  };

  // prologue: stage kt=0 and kt=1 (8 loads/thread outstanding), wait for kt=0
  STAGE(0, 0);
  STAGE(1, 1);
  asm volatile("s_waitcnt vmcnt(4)" ::: "memory");
  __builtin_amdgcn_s_barrier();

  floatx4 o_acc[2][8] = {};
  float m_i[2][4], l_i[2][4];
#pragma unroll
  for (int mt = 0; mt < 2; mt++)
#pragma unroll
    for (int r = 0; r < 4; r++) { m_i[mt][r] = -1e30f; l_i[mt][r] = 0.f; }
  ushort16* Pw = Ps[wave];

  for (int kt = 0; kt <= ktmax; ++kt) {
    const int cb = kt % 3;
    // depth-2 prefetch: issue tile kt+2 before compute of tile kt
    if (kt + 2 <= ktmax) STAGE(kt + 2, (kt + 2) % 3);

    const ushort16* KsC = &Ks[cb][0];
    const ushort16* VTC = &VT[cb][0];
    const bool active = (kt * 64 <= qrow0 + 31);
    if (active) {
      // S = Q K^T : K-frags reused across both m-tiles
      floatx4 sc[2][4] = {};
      __builtin_amdgcn_s_setprio(1);
#pragma unroll
      for (int nt = 0; nt < 4; nt++)
#pragma unroll
        for (int ks = 0; ks < 4; ks++) {
          short8 bk = *(const short8*)(KsC + (nt * 16 + l15) * 128 + (((ks * 4 + quad) ^ l15) * 8));
          sc[0][nt] = __builtin_amdgcn_mfma_f32_16x16x32_bf16(aq[0][ks], bk, sc[0][nt], 0, 0, 0);
          sc[1][nt] = __builtin_amdgcn_mfma_f32_16x16x32_bf16(aq[1][ks], bk, sc[1][nt], 0, 0, 0);
        }
      __builtin_amdgcn_s_setprio(0);

      // causal mask (only near the diagonal)
      if (kt * 64 + 63 > qrow0) {
#pragma unroll
        for (int mt = 0; mt < 2; mt++)
#pragma unroll
          for (int nt = 0; nt < 4; nt++)
#pragma unroll
            for (int r = 0; r < 4; r++)
              if (kt * 64 + nt * 16 + l15 > qrow0 + mt * 16 + quad * 4 + r) sc[mt][nt][r] = -1e30f;
      }

      // online softmax with T13 defer-max; rows quad*4+r shared by the 16 lanes of a quad
#pragma unroll
      for (int mt = 0; mt < 2; mt++) {
        float mx[4];
#pragma unroll
        for (int r = 0; r < 4; r++) {
          float m0 = fmaxf(fmaxf(sc[mt][0][r], sc[mt][1][r]), fmaxf(sc[mt][2][r], sc[mt][3][r]));
#pragma unroll
          for (int off = 1; off < 16; off <<= 1) m0 = fmaxf(m0, __shfl_xor(m0, off, 64));
          mx[r] = m0;
        }
        bool defer = true;
#pragma unroll
        for (int r = 0; r < 4; r++) defer = defer && (mx[r] - m_i[mt][r] <= 8.f);
        if (!__all(defer)) {
#pragma unroll
          for (int r = 0; r < 4; r++) {
            const float mn = fmaxf(m_i[mt][r], mx[r]);
            const float alpha = __expf(m_i[mt][r] - mn);
            m_i[mt][r] = mn;
            l_i[mt][r] *= alpha;
#pragma unroll
            for (int dt = 0; dt < 8; dt++) o_acc[mt][dt][r] *= alpha;
          }
        }
#pragma unroll
        for (int r = 0; r < 4; r++) {
          float s0 = 0.f;
          const int prow = mt * 16 + quad * 4 + r;
#pragma unroll
          for (int nt = 0; nt < 4; nt++) {
            const float p = __expf(sc[mt][nt][r] - m_i[mt][r]);
            s0 += p;
            const int key = nt * 16 + l15;
            Pw[prow * 64 + ((((key >> 3) ^ (prow & 7)) * 8) + (key & 7))] = f32_bf16(p);
          }
#pragma unroll
          for (int off = 1; off < 16; off <<= 1) s0 += __shfl_xor(s0, off, 64);
          l_i[mt][r] += s0;
        }
      }

      // O += P V : V^T-frags reused across both m-tiles (same-wave LDS W->R, DS in-order)
      __builtin_amdgcn_s_setprio(1);
#pragma unroll
      for (int ks2 = 0; ks2 < 2; ks2++) {
        short8 ap0 = *(const short8*)(Pw + l15 * 64 + (((ks2 * 4 + quad) ^ (l15 & 7)) * 8));
        short8 ap1 = *(const short8*)(Pw + (16 + l15) * 64 + (((ks2 * 4 + quad) ^ (l15 & 7)) * 8));
#pragma unroll
        for (int dt = 0; dt < 8; dt++) {
          const int d = dt * 16 + l15;
          short8 bv = *(const short8*)(VTC + d * 64 + (((ks2 * 4 + quad) ^ (d & 7)) * 8));
          o_acc[0][dt] = __builtin_amdgcn_mfma_f32_16x16x32_bf16(ap0, bv, o_acc[0][dt], 0, 0, 0);
          o_acc[1][dt] = __builtin_amdgcn_mfma_f32_16x16x32_bf16(ap1, bv, o_acc[1][dt], 0, 0, 0);
        }
      }
      __builtin_amdgcn_s_setprio(0);
    }

    // tile boundary: wait only for tile kt+1's loads (counted), then barrier.
    if (kt < ktmax) {
      if (kt + 2 <= ktmax) asm volatile("s_waitcnt vmcnt(4)" ::: "memory");
      else                 asm volatile("s_waitcnt vmcnt(0)" ::: "memory");
      __builtin_amdgcn_s_barrier();
    }
  }

  float vinv[2][4];
#pragma unroll
  for (int mt = 0; mt < 2; mt++)
#pragma unroll
    for (int r = 0; r < 4; r++) vinv[mt][r] = 1.f / l_i[mt][r];
#pragma unroll
  for (int mt = 0; mt < 2; mt++)
#pragma unroll
    for (int dt = 0; dt < 8; dt++)
#pragma unroll
      for (int r = 0; r < 4; r++)
        Cg[(size_t)(b * S_ + qrow0 + mt * 16 + quad * 4 + r) * 4096 + h * 128 + dt * 16 + l15] =
            f32_bf16(o_acc[mt][dt][r] * vinv[mt][r]);
}

extern "C" void kernel_launch(void* const* d_in, const int* in_sizes, int n_in,
                              void* d_out, int out_size, void* d_ws, size_t ws_size,
                              hipStream_t stream) {
  const float* hs   = (const float*)d_in[0];
  const float* cosT = (const float*)d_in[1];
  const float* sinT = (const float*)d_in[2];
  const float* Wq = (const float*)d_in[5];
  const float* Wk = (const float*)d_in[6];
  const float* Wv = (const float*)d_in[7];
  const float* Wo = (const float*)d_in[8];
  float* out = (float*)d_out;

  char* ws = (char*)d_ws;
  ushort16* hsB = (ushort16*)(ws);                      // 33.5 MB  (also reused as CB)
  ushort16* QB  = (ushort16*)(ws + 33554432);           // 33.5 MB
  ushort16* KB  = (ushort16*)(ws + 67108864);           // 8.4 MB
  ushort16* VB  = (ushort16*)(ws + 75497472);           // 8.4 MB
  ushort16* VTg = (ushort16*)(ws + 83886080);           // 8.4 MB
  ushort16* WB  = (ushort16*)(ws + 92274688);           // 33.5 MB (per-GEMM weight buf)
  ushort16* CB  = hsB;                                  // reuse hs region after V GEMM

  dim3 blk(256);
  cvt_bf16<<<dim3(16384), blk, 0, stream>>>(hs, (uint32*)hsB);
  cvt_bf16<<<dim3(16384), blk, 0, stream>>>(Wq, (uint32*)WB);
  gemm128<true,  true,  false><<<dim3(32, 32), blk, 0, stream>>>(hsB, WB, QB, 4096, cosT, sinT);
  cvt_bf16<<<dim3(4096),  blk, 0, stream>>>(Wk, (uint32*)WB);
  gemm128<true,  false, false><<<dim3(8, 32),  blk, 0, stream>>>(hsB, WB, KB, 1024, cosT, sinT);
  cvt_bf16<<<dim3(4096),  blk, 0, stream>>>(Wv, (uint32*)WB);
  gemm128<false, false, false><<<dim3(8, 32),  blk, 0, stream>>>(hsB, WB, VB, 1024, cosT, sinT);
  transp<<<dim3(16, 64), blk, 0, stream>>>(VB, VTg);
  flash_mfma<<<dim3(S_ / 256, 2 * NH_), dim3(512), 0, stream>>>(QB, KB, VTg, CB);
  cvt_bf16<<<dim3(16384), blk, 0, stream>>>(Wo, (uint32*)WB);
  gemm128<false, false, true><<<dim3(32, 32), blk, 0, stream>>>(CB, WB, out, 4096, cosT, sinT);
}